// Round 1
// baseline (9.727 us; speedup 1.0000x reference)
//
#include <hip/hip_runtime.h>
#include <hip/hip_bf16.h>

// LengthRegulator: d = round(dur) * (1 - pad); cumsum over tokens; output
// mel2token[b][p] = 1-based token index whose [cum_prev, cum) span contains p,
// 0 for p >= row total. Output dtype int32, shape (B, T_mel), T_mel = out_size/B.

#define T_TXT 512
#define BATCH 32

__global__ __launch_bounds__(T_TXT) void LengthRegulator_8169027797081_kernel(
    const float* __restrict__ dur, const int* __restrict__ pad,
    int* __restrict__ out, int T_mel) {
    __shared__ int cum[T_TXT];
    const int b = blockIdx.x;
    const int t = threadIdx.x;

    // load + round + mask padding
    float v = dur[b * T_TXT + t];
    int d = (int)rintf(v);
    d *= (1 - pad[b * T_TXT + t]);
    cum[t] = d;
    __syncthreads();

    // Hillis-Steele inclusive scan over 512 elements
    #pragma unroll
    for (int off = 1; off < T_TXT; off <<= 1) {
        int add = (t >= off) ? cum[t - off] : 0;
        __syncthreads();
        cum[t] += add;
        __syncthreads();
    }

    const int total = cum[T_TXT - 1];

    // Fill this row's T_mel outputs: binary search for first idx with cum[idx] > p
    for (int p = t; p < T_mel; p += T_TXT) {
        int val = 0;
        if (p < total) {
            int lo = 0, hi = T_TXT - 1;
            while (lo < hi) {
                int mid = (lo + hi) >> 1;
                if (cum[mid] > p) hi = mid; else lo = mid + 1;
            }
            val = lo + 1;
        }
        out[b * T_mel + p] = val;
    }
}

extern "C" void kernel_launch(void* const* d_in, const int* in_sizes, int n_in,
                              void* d_out, int out_size, void* d_ws, size_t ws_size,
                              hipStream_t stream) {
    const float* dur = (const float*)d_in[0];
    const int* pad = (const int*)d_in[1];
    int* out = (int*)d_out;
    const int T_mel = out_size / BATCH;
    LengthRegulator_8169027797081_kernel<<<BATCH, T_TXT, 0, stream>>>(dur, pad, out, T_mel);
}